// Round 6
// baseline (353.924 us; speedup 1.0000x reference)
//
#include <hip/hip_runtime.h>
#include <cstdint>
#include <cstddef>

#define S_LEN 384
#define BATCH 256
#define DIM   192     // HH*WW
#define HID   100
#define G4    400     // 4*HID
#define NCLS  250

#define WSTEPS 16     // z-tile window (MFMA M-dim = 16 timesteps)
#define NWIN   24     // 384 / 16
#define NTILES 28     // 448 cols (4 gates x 112) / 16
#define NKC    6      // 192 / 32 k-chunks

#define LOG2E  1.4426950408889634f
#define LOG2E2 2.8853900817779268f

typedef float    f32x4   __attribute__((ext_vector_type(4)));
typedef short    bf16x8  __attribute__((ext_vector_type(8)));
typedef _Float16 half2_t __attribute__((ext_vector_type(2)));
typedef _Float16 f16x4   __attribute__((ext_vector_type(4)));
typedef _Float16 f16x8   __attribute__((ext_vector_type(8)));

static __device__ __forceinline__ unsigned short f2bf(float f) {
    unsigned u = __float_as_uint(f);
    return (unsigned short)((u + 0x7FFFu + ((u >> 16) & 1u)) >> 16);   // RNE
}

// packed f32x2 -> bf16x2 (RNE), gfx950 has no builtin (learn_hip m240)
static __device__ __forceinline__ unsigned cvtpk(float a, float b) {
    unsigned r;
    asm("v_cvt_pk_bf16_f32 %0, %1, %2" : "=v"(r) : "v"(a), "v"(b));
    return r;
}

// DPP quad_perm cross-lane (VALU ~2cyc)
template<int CTRL>
static __device__ __forceinline__ float fdpp(float x) {
    return __int_as_float(
        __builtin_amdgcn_mov_dpp(__float_as_int(x), CTRL, 0xF, 0xF, true));
}
#define DPP_X1 0xB1   // quad_perm [1,0,3,2]  == xor 1
#define DPP_X2 0x4E   // quad_perm [2,3,0,1]  == xor 2
#define DPP_B0 0x00   // quad_perm [0,0,0,0]  broadcast lane0 of quad
#define DPP_B1 0x55   // quad_perm [1,1,1,1]
#define DPP_B2 0xAA   // quad_perm [2,2,2,2]
#define DPP_B3 0xFF   // quad_perm [3,3,3,3]

// ---------------------------------------------------------------------------
// Prep:
//  blocks [0,336): Wf — W as MFMA B-fragments (bf16), verified r5 mapping:
//    Wf[((ct*6+kc)*64+lane)*8+e] = bf16(W[d][gate*100+unit]),
//    gate=ct/7, unit=(ct%7)*16+(lane&15) (0-pad unit>=100),
//    d = kc*32 + (lane>>4)*8 + e.
//  blocks [336,419): biasf[448] (tile-ordered bias, 0-padded) + Ut4
//    (unchanged verified U fragment layout for the scan).
// ---------------------------------------------------------------------------
__global__ void prep(const float* __restrict__ W, const float* __restrict__ U,
                     const float* __restrict__ bias,
                     unsigned short* __restrict__ Wf, float* __restrict__ biasf,
                     half2_t* __restrict__ Ut4)
{
    int bid = blockIdx.x;
    if (bid < 336) {
        int i = bid * 256 + threadIdx.x;          // 336*256 = 86016 exactly
        int e    = i & 7;
        int fi   = i >> 3;
        int lane = fi & 63;
        int ck   = fi >> 6;                       // (ct*6+kc) < 168
        int ct   = ck / 6, kc = ck - ct * 6;
        int m    = lane & 15, q = lane >> 4;
        int gate = ct / 7, jj = ct - gate * 7;
        int unit = jj * 16 + m;
        int d    = kc * 32 + q * 8 + e;           // < 192 always
        float v  = (unit < HID) ? W[(size_t)d * G4 + gate * HID + unit] : 0.0f;
        Wf[i] = f2bf(v);
    } else {
        int i = (bid - 336) * 256 + threadIdx.x;  // 448 + 20800 = 21248
        if (i < 448) {
            int ct = i >> 4, mm = i & 15;
            int gate = ct / 7, jj = ct - gate * 7;
            int unit = jj * 16 + mm;
            biasf[i] = (unit < HID) ? bias[gate * HID + unit] : 0.0f;
        } else {
            int i2 = i - 448;
            if (i2 >= 20800) return;
            int n    = i2 / 208;
            int rem  = i2 - n * 208;
            int q    = rem / 52;
            int rem2 = rem - q * 52;
            int mm   = rem2 / 13;
            int r    = rem2 - mm * 13;
            int col  = (q ^ mm) * HID + n;
            int j0   = 26 * q + 2 * r;
            half2_t v;
            v.x = (_Float16)(j0     < HID ? U[(size_t)j0       * G4 + col] : 0.0f);
            v.y = (_Float16)(j0 + 1 < HID ? U[(size_t)(j0 + 1) * G4 + col] : 0.0f);
            Ut4[i2] = v;
        }
    }
}

// ---------------------------------------------------------------------------
// Fused kernel, round 6: producer/consumer wave specialization.
//   Waves 0-6 (448 thr): the VERIFIED r1 scan core, untouched — z read from
//     LDS zbuf (16-step windows, double-buffered). 16 barriers per window
//     (one per step).
//   Wave 7: dedicated producer. Per window it computes the NEXT window's
//     z-tile (28 col-tiles of 16 steps, 6 MFMA each) spread over the same
//     16 barrier slots (<=2 tiles/slot, ~600cy work vs ~1100cy step). Its
//     MFMA + Wf/x load latency now OVERLAPS the scan waves' execution
//     instead of extending the lockstep barrier critical path (the r5
//     mistake: inline produce cost +65us because all waves paid its
//     latency inside the same barrier phase).
//   Barrier counts match exactly: 1 (prologue) + 24*16 + 1 (tail) = 386
//   on both branches; branch condition is wave-uniform (w==7).
// ---------------------------------------------------------------------------
__global__ __launch_bounds__(512)
__attribute__((amdgpu_waves_per_eu(2, 2)))
void scan_fused(const float* __restrict__ x, const unsigned short* __restrict__ Wf,
                const half2_t* __restrict__ Ut4, const float* __restrict__ biasf,
                const float* __restrict__ Wd, const float* __restrict__ bd,
                float* __restrict__ out)
{
    __shared__ __align__(16) _Float16 h2[2][4][40];
    __shared__ __align__(16) float hf32[HID];
    __shared__ __align__(16) _Float16 zbuf[2][448 * WSTEPS];   // 28.7 KB

    const int b    = blockIdx.x;
    const int t    = threadIdx.x;
    const int lane = t & 63;
    const int w    = t >> 6;

    if (t < 320) ((_Float16*)h2)[t] = (_Float16)0.f;   // zero both h bufs

    if (w == 7) {
        // ===================== PRODUCER WAVE =====================
        const int pm = lane & 15;        // step row within window
        const int pq = lane >> 4;        // k-slice
        const float* __restrict__ xb = x + (size_t)b * S_LEN * DIM;
        float4 xv[NKC][2];               // next window's x rows
        bf16x8 Af[NKC];                  // current produce window's A frags

        auto loadx = [&](int s0) {
            int xr = s0 + pm;
#pragma unroll
            for (int kc = 0; kc < NKC; ++kc) {
                const float* p = xb + (size_t)xr * DIM + kc * 32 + pq * 8;
                xv[kc][0] = *(const float4*)p;
                xv[kc][1] = *(const float4*)(p + 4);
            }
        };
        auto cvt = [&]() {
#pragma unroll
            for (int kc = 0; kc < NKC; ++kc) {
                int4 ai;
                ai.x = (int)cvtpk(xv[kc][0].x, xv[kc][0].y);
                ai.y = (int)cvtpk(xv[kc][0].z, xv[kc][0].w);
                ai.z = (int)cvtpk(xv[kc][1].x, xv[kc][1].y);
                ai.w = (int)cvtpk(xv[kc][1].z, xv[kc][1].w);
                Af[kc] = *(bf16x8*)&ai;
            }
        };
        auto ptile = [&](int ct, int nb) {
            float bvv = biasf[ct * 16 + pm];          // hides under MFMA chain
            const unsigned short* bp = Wf + ((size_t)ct * (NKC * 64) + lane) * 8;
            f32x4 acc = {0.f, 0.f, 0.f, 0.f};
#pragma unroll
            for (int kc = 0; kc < NKC; ++kc) {
                bf16x8 Bf = *(const bf16x8*)(bp + (size_t)kc * 512);
                acc = __builtin_amdgcn_mfma_f32_16x16x32_bf16(Af[kc], Bf, acc, 0, 0, 0);
            }
            f16x4 zq;
            zq[0] = (_Float16)(acc[0] + bvv);
            zq[1] = (_Float16)(acc[1] + bvv);
            zq[2] = (_Float16)(acc[2] + bvv);
            zq[3] = (_Float16)(acc[3] + bvv);
            *(f16x4*)&zbuf[nb][(ct * 16 + pm) * WSTEPS + pq * 4] = zq;
        };

        // prologue: window 0 into zbuf[0]; prefetch x(window 1)
        loadx(0);
        cvt();
        for (int ct = 0; ct < NTILES; ++ct) ptile(ct, 0);
        loadx(WSTEPS);
        __syncthreads();                              // barrier #0

        for (int j = 0; j < NWIN; ++j) {
            const bool hasNext = (j < NWIN - 1);
            if (hasNext) cvt();                       // x(j+1) -> Af
            if (j < NWIN - 2) loadx((j + 2) * WSTEPS);
            const int nb = (j + 1) & 1;
#pragma unroll 1
            for (int k = 0; k < WSTEPS; ++k) {        // 16 slots == 16 barriers
                if (hasNext) {
                    ptile(k, nb);
                    if (k < NTILES - WSTEPS) ptile(WSTEPS + k, nb);
                }
                __syncthreads();
            }
        }
        __syncthreads();                              // matches scan tail barrier
    } else {
        // ===================== SCAN WAVES (verified r1 core) =====================
        const int q  = t & 3;
        const int nr = t >> 2;                   // 0..111
        const bool active = (nr < HID);
        const int n  = active ? nr : HID - 1;
        const int wq = n / 26, wi = n - wq * 26;

        half2_t Uc[4][13];
#pragma unroll
        for (int mm = 0; mm < 4; ++mm) {
            const half2_t* up = Ut4 + (size_t)((n * 4 + q) * 4 + mm) * 13;
#pragma unroll
            for (int r = 0; r < 13; ++r) Uc[mm][r] = up[r];
        }

        float c = 0.f;
        __syncthreads();                              // barrier #0

        const float scale = (q == 2) ? -LOG2E2 : -LOG2E;
        const float Aact  = (q == 2) ? 2.0f : 1.0f;
        const float Bact  = (q == 2) ? -1.0f : 0.0f;

        float hn_last = 0.f;

        auto step = [&](float zk, int cur) {
            const _Float16* hb = &h2[cur][q][0];
            f16x8   g0 = *(const f16x8*)(hb);
            f16x8   g1 = *(const f16x8*)(hb + 8);
            f16x8   g2 = *(const f16x8*)(hb + 16);
            half2_t g3 = *(const half2_t*)(hb + 24);
            half2_t hp[13];
            hp[0]  = __builtin_shufflevector(g0, g0, 0, 1);
            hp[1]  = __builtin_shufflevector(g0, g0, 2, 3);
            hp[2]  = __builtin_shufflevector(g0, g0, 4, 5);
            hp[3]  = __builtin_shufflevector(g0, g0, 6, 7);
            hp[4]  = __builtin_shufflevector(g1, g1, 0, 1);
            hp[5]  = __builtin_shufflevector(g1, g1, 2, 3);
            hp[6]  = __builtin_shufflevector(g1, g1, 4, 5);
            hp[7]  = __builtin_shufflevector(g1, g1, 6, 7);
            hp[8]  = __builtin_shufflevector(g2, g2, 0, 1);
            hp[9]  = __builtin_shufflevector(g2, g2, 2, 3);
            hp[10] = __builtin_shufflevector(g2, g2, 4, 5);
            hp[11] = __builtin_shufflevector(g2, g2, 6, 7);
            hp[12] = g3;

            float p0 = 0.f, p1 = 0.f, p2 = 0.f, p3 = 0.f;
#pragma unroll
            for (int r = 0; r < 13; ++r) {
                p0 = __builtin_amdgcn_fdot2(Uc[0][r], hp[r], p0, false);
                p1 = __builtin_amdgcn_fdot2(Uc[1][r], hp[r], p1, false);
                p2 = __builtin_amdgcn_fdot2(Uc[2][r], hp[r], p2, false);
                p3 = __builtin_amdgcn_fdot2(Uc[3][r], hp[r], p3, false);
            }
            float s0 = p0 + fdpp<DPP_X1>(p1);
            float s2 = p2 + fdpp<DPP_X1>(p3);
            float a  = s0 + fdpp<DPP_X2>(s2) + zk;

            float v = fmaf(Aact,
                           __builtin_amdgcn_rcpf(1.0f + __builtin_amdgcn_exp2f(scale * a)),
                           Bact);

            float bi = fdpp<DPP_B0>(v);
            float bf = fdpp<DPP_B1>(v);
            float bg = fdpp<DPP_B2>(v);
            float bo = fdpp<DPP_B3>(v);

            c = fmaf(bf, c, bi * bg);
            float tc = fmaf(2.0f,
                            __builtin_amdgcn_rcpf(1.0f + __builtin_amdgcn_exp2f(-LOG2E2 * c)),
                            -1.0f);
            float hn = bo * tc;
            if (q == 0 && active) h2[cur ^ 1][wq][wi] = (_Float16)hn;
            hn_last = hn;
            __syncthreads();
        };

        const int col = q * 112 + n;             // zbuf column (gate q, unit n)

        for (int j = 0; j < NWIN; ++j) {
            f16x8 zA = *(const f16x8*)&zbuf[j & 1][col * WSTEPS];
            f16x8 zB = *(const f16x8*)&zbuf[j & 1][col * WSTEPS + 8];
#pragma unroll
            for (int k = 0; k < 8; ++k) step((float)zA[k], k & 1);
#pragma unroll
            for (int k = 0; k < 8; ++k) step((float)zB[k], k & 1);
        }

        // ---- classifier tail ----
        if (q == 0 && active) hf32[n] = hn_last;
        __syncthreads();                              // tail barrier
        if (t < NCLS) {
            float acc2 = bd[t];
            const float4* h4 = (const float4*)hf32;
#pragma unroll 5
            for (int j4 = 0; j4 < 25; ++j4) {
                float4 hv = h4[j4];
                acc2 = fmaf(hv.x, Wd[(size_t)(4 * j4 + 0) * NCLS + t], acc2);
                acc2 = fmaf(hv.y, Wd[(size_t)(4 * j4 + 1) * NCLS + t], acc2);
                acc2 = fmaf(hv.z, Wd[(size_t)(4 * j4 + 2) * NCLS + t], acc2);
                acc2 = fmaf(hv.w, Wd[(size_t)(4 * j4 + 3) * NCLS + t], acc2);
            }
            out[(size_t)b * NCLS + t] = acc2;
        }
    }
}

// ---------------------------------------------------------------------------
extern "C" void kernel_launch(void* const* d_in, const int* in_sizes, int n_in,
                              void* d_out, int out_size, void* d_ws, size_t ws_size,
                              hipStream_t stream)
{
    const float* x    = (const float*)d_in[0];
    const float* W    = (const float*)d_in[1];
    const float* U    = (const float*)d_in[2];
    const float* bias = (const float*)d_in[3];
    const float* Wd   = (const float*)d_in[4];
    const float* bd   = (const float*)d_in[5];
    float* out = (float*)d_out;

    // ws (dwords): [Wf 43008][biasf 448][Ut4 20800]
    unsigned int* wsb = (unsigned int*)d_ws;
    unsigned short* Wf    = (unsigned short*)wsb;
    float*          biasf = (float*)(wsb + 43008);
    half2_t*        Ut4   = (half2_t*)(wsb + 43456);

    prep<<<419, 256, 0, stream>>>(W, U, bias, Wf, biasf, Ut4);
    scan_fused<<<BATCH, 512, 0, stream>>>(x, Wf, Ut4, biasf, Wd, bd, out);
}

// Round 7
// 309.059 us; speedup vs baseline: 1.1452x; 1.1452x over previous
//
#include <hip/hip_runtime.h>
#include <cstdint>
#include <cstddef>

#define S_LEN 384
#define BATCH 256
#define DIM   192     // HH*WW
#define HID   100
#define G4    400     // 4*HID
#define NCLS  250

#define WSTEPS 16     // z-tile window (MFMA M-dim = 16 timesteps)
#define NWIN   24     // 384 / 16
#define NTILES 28     // 448 cols (4 gates x 112) / 16
#define NKC    6      // 192 / 32 k-chunks

#define LOG2E  1.4426950408889634f
#define LOG2E2 2.8853900817779268f

typedef float    f32x4   __attribute__((ext_vector_type(4)));
typedef short    bf16x8  __attribute__((ext_vector_type(8)));
typedef _Float16 half2_t __attribute__((ext_vector_type(2)));
typedef _Float16 f16x4   __attribute__((ext_vector_type(4)));
typedef _Float16 f16x8   __attribute__((ext_vector_type(8)));

static __device__ __forceinline__ unsigned short f2bf(float f) {
    unsigned u = __float_as_uint(f);
    return (unsigned short)((u + 0x7FFFu + ((u >> 16) & 1u)) >> 16);   // RNE
}

// packed f32x2 -> bf16x2 (RNE), gfx950 has no builtin (learn_hip m240)
static __device__ __forceinline__ unsigned cvtpk(float a, float b) {
    unsigned r;
    asm("v_cvt_pk_bf16_f32 %0, %1, %2" : "=v"(r) : "v"(a), "v"(b));
    return r;
}

// DPP quad_perm cross-lane (VALU ~2cyc)
template<int CTRL>
static __device__ __forceinline__ float fdpp(float x) {
    return __int_as_float(
        __builtin_amdgcn_mov_dpp(__float_as_int(x), CTRL, 0xF, 0xF, true));
}
#define DPP_X1 0xB1   // quad_perm [1,0,3,2]  == xor 1
#define DPP_X2 0x4E   // quad_perm [2,3,0,1]  == xor 2
#define DPP_B0 0x00   // quad_perm [0,0,0,0]  broadcast lane0 of quad
#define DPP_B1 0x55   // quad_perm [1,1,1,1]
#define DPP_B2 0xAA   // quad_perm [2,2,2,2]
#define DPP_B3 0xFF   // quad_perm [3,3,3,3]

// ---------------------------------------------------------------------------
// Prep (unchanged, verified):
//  blocks [0,336): Wf — W as MFMA B-fragments (bf16):
//    Wf[((ct*6+kc)*64+lane)*8+e] = bf16(W[d][gate*100+unit]),
//    gate=ct/7, unit=(ct%7)*16+(lane&15) (0-pad unit>=100),
//    d = kc*32 + (lane>>4)*8 + e.
//  blocks [336,419): biasf[448] (tile-ordered bias, 0-padded) + Ut4
//    (unchanged verified U fragment layout for the scan).
// ---------------------------------------------------------------------------
__global__ void prep(const float* __restrict__ W, const float* __restrict__ U,
                     const float* __restrict__ bias,
                     unsigned short* __restrict__ Wf, float* __restrict__ biasf,
                     half2_t* __restrict__ Ut4)
{
    int bid = blockIdx.x;
    if (bid < 336) {
        int i = bid * 256 + threadIdx.x;          // 336*256 = 86016 exactly
        int e    = i & 7;
        int fi   = i >> 3;
        int lane = fi & 63;
        int ck   = fi >> 6;                       // (ct*6+kc) < 168
        int ct   = ck / 6, kc = ck - ct * 6;
        int m    = lane & 15, q = lane >> 4;
        int gate = ct / 7, jj = ct - gate * 7;
        int unit = jj * 16 + m;
        int d    = kc * 32 + q * 8 + e;           // < 192 always
        float v  = (unit < HID) ? W[(size_t)d * G4 + gate * HID + unit] : 0.0f;
        Wf[i] = f2bf(v);
    } else {
        int i = (bid - 336) * 256 + threadIdx.x;  // 448 + 20800 = 21248
        if (i < 448) {
            int ct = i >> 4, mm = i & 15;
            int gate = ct / 7, jj = ct - gate * 7;
            int unit = jj * 16 + mm;
            biasf[i] = (unit < HID) ? bias[gate * HID + unit] : 0.0f;
        } else {
            int i2 = i - 448;
            if (i2 >= 20800) return;
            int n    = i2 / 208;
            int rem  = i2 - n * 208;
            int q    = rem / 52;
            int rem2 = rem - q * 52;
            int mm   = rem2 / 13;
            int r    = rem2 - mm * 13;
            int col  = (q ^ mm) * HID + n;
            int j0   = 26 * q + 2 * r;
            half2_t v;
            v.x = (_Float16)(j0     < HID ? U[(size_t)j0       * G4 + col] : 0.0f);
            v.y = (_Float16)(j0 + 1 < HID ? U[(size_t)(j0 + 1) * G4 + col] : 0.0f);
            Ut4[i2] = v;
        }
    }
}

// ---------------------------------------------------------------------------
// Fused kernel, round 7: producer/consumer with TWO producer waves.
//   r6 failure mode (measured): one producer wave had ~1.75 tiles/slot,
//   each tile a serial 6-deep MFMA chain on L2 loads (~850-900cy/slot) —
//   the block barrier became producer-limited (1730cy/step, VALUBusy 36%).
//   Fix: 576 threads (9 waves). Waves 0-6: VERIFIED scan core, untouched.
//   Waves 7,8: producers, 14 tiles each per window => <=1 tile/slot
//   (~400-450cy) — back under the scan's ~1100cy step, so the barrier
//   critical path is scan-limited again. Both producers load the same x
//   window (L1-hot, negligible).
//   Barrier counts match on all waves: 1 + 24*16 + 1 = 386.
// ---------------------------------------------------------------------------
__global__ __launch_bounds__(576)
__attribute__((amdgpu_waves_per_eu(2)))
void scan_fused(const float* __restrict__ x, const unsigned short* __restrict__ Wf,
                const half2_t* __restrict__ Ut4, const float* __restrict__ biasf,
                const float* __restrict__ Wd, const float* __restrict__ bd,
                float* __restrict__ out)
{
    __shared__ __align__(16) _Float16 h2[2][4][40];
    __shared__ __align__(16) float hf32[HID];
    __shared__ __align__(16) _Float16 zbuf[2][448 * WSTEPS];   // 28.7 KB

    const int b    = blockIdx.x;
    const int t    = threadIdx.x;
    const int lane = t & 63;
    const int w    = t >> 6;

    if (t < 320) ((_Float16*)h2)[t] = (_Float16)0.f;   // zero both h bufs

    if (w >= 7) {
        // ===================== PRODUCER WAVES (2) =====================
        const int po = w - 7;            // 0: tiles [0,14), 1: tiles [14,28)
        const int pm = lane & 15;        // step row within window
        const int pq = lane >> 4;        // k-slice
        const float* __restrict__ xb = x + (size_t)b * S_LEN * DIM;
        float4 xv[NKC][2];               // next window's x rows
        bf16x8 Af[NKC];                  // current produce window's A frags

        auto loadx = [&](int s0) {
            int xr = s0 + pm;
#pragma unroll
            for (int kc = 0; kc < NKC; ++kc) {
                const float* p = xb + (size_t)xr * DIM + kc * 32 + pq * 8;
                xv[kc][0] = *(const float4*)p;
                xv[kc][1] = *(const float4*)(p + 4);
            }
        };
        auto cvt = [&]() {
#pragma unroll
            for (int kc = 0; kc < NKC; ++kc) {
                int4 ai;
                ai.x = (int)cvtpk(xv[kc][0].x, xv[kc][0].y);
                ai.y = (int)cvtpk(xv[kc][0].z, xv[kc][0].w);
                ai.z = (int)cvtpk(xv[kc][1].x, xv[kc][1].y);
                ai.w = (int)cvtpk(xv[kc][1].z, xv[kc][1].w);
                Af[kc] = *(bf16x8*)&ai;
            }
        };
        auto ptile = [&](int ct, int nb) {
            float bvv = biasf[ct * 16 + pm];          // L2-hot, hides in chain
            const unsigned short* bp = Wf + ((size_t)ct * (NKC * 64) + lane) * 8;
            f32x4 acc = {0.f, 0.f, 0.f, 0.f};
#pragma unroll
            for (int kc = 0; kc < NKC; ++kc) {
                bf16x8 Bf = *(const bf16x8*)(bp + (size_t)kc * 512);
                acc = __builtin_amdgcn_mfma_f32_16x16x32_bf16(Af[kc], Bf, acc, 0, 0, 0);
            }
            f16x4 zq;
            zq[0] = (_Float16)(acc[0] + bvv);
            zq[1] = (_Float16)(acc[1] + bvv);
            zq[2] = (_Float16)(acc[2] + bvv);
            zq[3] = (_Float16)(acc[3] + bvv);
            *(f16x4*)&zbuf[nb][(ct * 16 + pm) * WSTEPS + pq * 4] = zq;
        };

        // prologue: window 0 into zbuf[0]; prefetch x(window 1)
        loadx(0);
        cvt();
        for (int ct = po * 14; ct < po * 14 + 14; ++ct) ptile(ct, 0);
        loadx(WSTEPS);
        __syncthreads();                              // barrier #0

        for (int j = 0; j < NWIN; ++j) {
            const bool hasNext = (j < NWIN - 1);
            if (hasNext) cvt();                       // x(j+1) -> Af
            if (j < NWIN - 2) loadx((j + 2) * WSTEPS);
            const int nb = (j + 1) & 1;
#pragma unroll 1
            for (int k = 0; k < WSTEPS; ++k) {        // 16 slots == 16 barriers
                if (hasNext && k < 14) ptile(po * 14 + k, nb);
                __syncthreads();
            }
        }
        __syncthreads();                              // matches scan tail barrier
    } else {
        // ===================== SCAN WAVES (verified r1 core) =====================
        const int q  = t & 3;
        const int nr = t >> 2;                   // 0..111
        const bool active = (nr < HID);
        const int n  = active ? nr : HID - 1;
        const int wq = n / 26, wi = n - wq * 26;

        half2_t Uc[4][13];
#pragma unroll
        for (int mm = 0; mm < 4; ++mm) {
            const half2_t* up = Ut4 + (size_t)((n * 4 + q) * 4 + mm) * 13;
#pragma unroll
            for (int r = 0; r < 13; ++r) Uc[mm][r] = up[r];
        }

        float c = 0.f;
        __syncthreads();                              // barrier #0

        const float scale = (q == 2) ? -LOG2E2 : -LOG2E;
        const float Aact  = (q == 2) ? 2.0f : 1.0f;
        const float Bact  = (q == 2) ? -1.0f : 0.0f;

        float hn_last = 0.f;

        auto step = [&](float zk, int cur) {
            const _Float16* hb = &h2[cur][q][0];
            f16x8   g0 = *(const f16x8*)(hb);
            f16x8   g1 = *(const f16x8*)(hb + 8);
            f16x8   g2 = *(const f16x8*)(hb + 16);
            half2_t g3 = *(const half2_t*)(hb + 24);
            half2_t hp[13];
            hp[0]  = __builtin_shufflevector(g0, g0, 0, 1);
            hp[1]  = __builtin_shufflevector(g0, g0, 2, 3);
            hp[2]  = __builtin_shufflevector(g0, g0, 4, 5);
            hp[3]  = __builtin_shufflevector(g0, g0, 6, 7);
            hp[4]  = __builtin_shufflevector(g1, g1, 0, 1);
            hp[5]  = __builtin_shufflevector(g1, g1, 2, 3);
            hp[6]  = __builtin_shufflevector(g1, g1, 4, 5);
            hp[7]  = __builtin_shufflevector(g1, g1, 6, 7);
            hp[8]  = __builtin_shufflevector(g2, g2, 0, 1);
            hp[9]  = __builtin_shufflevector(g2, g2, 2, 3);
            hp[10] = __builtin_shufflevector(g2, g2, 4, 5);
            hp[11] = __builtin_shufflevector(g2, g2, 6, 7);
            hp[12] = g3;

            float p0 = 0.f, p1 = 0.f, p2 = 0.f, p3 = 0.f;
#pragma unroll
            for (int r = 0; r < 13; ++r) {
                p0 = __builtin_amdgcn_fdot2(Uc[0][r], hp[r], p0, false);
                p1 = __builtin_amdgcn_fdot2(Uc[1][r], hp[r], p1, false);
                p2 = __builtin_amdgcn_fdot2(Uc[2][r], hp[r], p2, false);
                p3 = __builtin_amdgcn_fdot2(Uc[3][r], hp[r], p3, false);
            }
            float s0 = p0 + fdpp<DPP_X1>(p1);
            float s2 = p2 + fdpp<DPP_X1>(p3);
            float a  = s0 + fdpp<DPP_X2>(s2) + zk;

            float v = fmaf(Aact,
                           __builtin_amdgcn_rcpf(1.0f + __builtin_amdgcn_exp2f(scale * a)),
                           Bact);

            float bi = fdpp<DPP_B0>(v);
            float bf = fdpp<DPP_B1>(v);
            float bg = fdpp<DPP_B2>(v);
            float bo = fdpp<DPP_B3>(v);

            c = fmaf(bf, c, bi * bg);
            float tc = fmaf(2.0f,
                            __builtin_amdgcn_rcpf(1.0f + __builtin_amdgcn_exp2f(-LOG2E2 * c)),
                            -1.0f);
            float hn = bo * tc;
            if (q == 0 && active) h2[cur ^ 1][wq][wi] = (_Float16)hn;
            hn_last = hn;
            __syncthreads();
        };

        const int col = q * 112 + n;             // zbuf column (gate q, unit n)

        for (int j = 0; j < NWIN; ++j) {
            f16x8 zA = *(const f16x8*)&zbuf[j & 1][col * WSTEPS];
            f16x8 zB = *(const f16x8*)&zbuf[j & 1][col * WSTEPS + 8];
#pragma unroll
            for (int k = 0; k < 8; ++k) step((float)zA[k], k & 1);
#pragma unroll
            for (int k = 0; k < 8; ++k) step((float)zB[k], k & 1);
        }

        // ---- classifier tail ----
        if (q == 0 && active) hf32[n] = hn_last;
        __syncthreads();                              // tail barrier
        if (t < NCLS) {
            float acc2 = bd[t];
            const float4* h4 = (const float4*)hf32;
#pragma unroll 5
            for (int j4 = 0; j4 < 25; ++j4) {
                float4 hv = h4[j4];
                acc2 = fmaf(hv.x, Wd[(size_t)(4 * j4 + 0) * NCLS + t], acc2);
                acc2 = fmaf(hv.y, Wd[(size_t)(4 * j4 + 1) * NCLS + t], acc2);
                acc2 = fmaf(hv.z, Wd[(size_t)(4 * j4 + 2) * NCLS + t], acc2);
                acc2 = fmaf(hv.w, Wd[(size_t)(4 * j4 + 3) * NCLS + t], acc2);
            }
            out[(size_t)b * NCLS + t] = acc2;
        }
    }
}

// ---------------------------------------------------------------------------
extern "C" void kernel_launch(void* const* d_in, const int* in_sizes, int n_in,
                              void* d_out, int out_size, void* d_ws, size_t ws_size,
                              hipStream_t stream)
{
    const float* x    = (const float*)d_in[0];
    const float* W    = (const float*)d_in[1];
    const float* U    = (const float*)d_in[2];
    const float* bias = (const float*)d_in[3];
    const float* Wd   = (const float*)d_in[4];
    const float* bd   = (const float*)d_in[5];
    float* out = (float*)d_out;

    // ws (dwords): [Wf 43008][biasf 448][Ut4 20800]
    unsigned int* wsb = (unsigned int*)d_ws;
    unsigned short* Wf    = (unsigned short*)wsb;
    float*          biasf = (float*)(wsb + 43008);
    half2_t*        Ut4   = (half2_t*)(wsb + 43456);

    prep<<<419, 256, 0, stream>>>(W, U, bias, Wf, biasf, Ut4);
    scan_fused<<<BATCH, 576, 0, stream>>>(x, Wf, Ut4, biasf, Wd, bd, out);
}